// Round 6
// baseline (119.249 us; speedup 1.0000x reference)
//
#include <hip/hip_runtime.h>
#include <math.h>

#define SPW 2          // samples per wave
#define WPB 16         // waves per block -> 1024 threads, grid = 512 = 2 blocks/CU
#define NTHR (WPB * 64)

__global__ __launch_bounds__(NTHR, 8) void hybridqrc_kernel(
    const float* __restrict__ xs,  const float* __restrict__ xl,
    const float* __restrict__ csw, const float* __restrict__ csb,
    const float* __restrict__ lsw, const float* __restrict__ lsb,
    const float* __restrict__ clw, const float* __restrict__ clb,
    const float* __restrict__ llw, const float* __restrict__ llb,
    const float* __restrict__ qw,  const float* __restrict__ fc1w,
    const float* __restrict__ fc1b,const float* __restrict__ fc2w,
    const float* __restrict__ fc2b,float* __restrict__ out, int B)
{
    // ---- LDS: both linear-weight matrices, channel-interleaved + 12 gates ----
    // lsw_s: [(q*4+c4)*256 + w*4 + (c&3)]  -> float4 read = channels 4c4..4c4+3
    // llw_s: [(q*8+c2)*256 + (j>>1)*4 + (c&1)*2 + (j&1)]
    //        -> float4 read = {p0w,p1w} for channels 2c2, 2c2+1
    __shared__ float lsw_s[6144];    // 24 KB
    __shared__ float llw_s[12288];   // 48 KB
    __shared__ float4 gme[24];       // [gate*2+bit] = (own_r, own_i, oth_r, oth_i)
    const int tid = threadIdx.x;
    const int lane = tid & 63;
    const int wave = blockIdx.x * WPB + (tid >> 6);
    const int base = wave * SPW;

    // issue per-wave input loads early (independent of LDS staging)
    float xsv[SPW];
    float4 xlv[SPW];
#pragma unroll
    for (int i = 0; i < SPW; i++) {
        xsv[i] = xs[(base + i) * 64 + lane];
        xlv[i] = reinterpret_cast<const float4*>(xl + (size_t)(base + i) * 256)[lane];
    }

#pragma unroll
    for (int it = 0; it < 6; it++) {
        int k = it * NTHR + tid;                 // k = q*1024 + c*64 + w
        int w = k & 63, c = (k >> 6) & 15, q = k >> 10;
        lsw_s[(q * 4 + (c >> 2)) * 256 + w * 4 + (c & 3)] = lsw[k];
    }
#pragma unroll
    for (int it = 0; it < 12; it++) {
        int k = it * NTHR + tid;                 // k = q*2048 + c*128 + j
        int j = k & 127, c = (k >> 7) & 15, q = k >> 11;
        llw_s[(q * 8 + (c >> 1)) * 256 + (j >> 1) * 4 + (c & 1) * 2 + (j & 1)] = llw[k];
    }
    if (tid < 24) {
        int g = tid >> 1, bit = tid & 1;
        float phi = qw[g * 3 + 0], th = qw[g * 3 + 1], om = qw[g * 3 + 2];
        float a = 0.5f * (phi + om), b = 0.5f * (phi - om);
        float ca = cosf(a), sa = sinf(a);
        float cb = cosf(b), sb = sinf(b);
        float ct = cosf(0.5f * th), st = sinf(0.5f * th);
        float4 v;
        if (bit) { v.x = ca * ct; v.y =  sa * ct; v.z =  cb * st; v.w = -sb * st; }
        else     { v.x = ca * ct; v.y = -sa * ct; v.z = -cb * st; v.w = -sb * st; }
        gme[tid] = v;
    }
    __syncthreads();

    if (base >= B) return;

    // ---- fused CNOT-ring permutations (lane-only, sample-independent) ----
    int perm0, perm1;
    {
        int y = lane;
#pragma unroll
        for (int j = 5; j >= 0; j--) {
            const int t = (j + 1) % 6;
            y ^= (y & (1 << (5 - j))) ? (1 << (5 - t)) : 0;
        }
        perm0 = y;
        y = lane;
#pragma unroll
        for (int j = 5; j >= 0; j--) {
            const int t = (j + 2) % 6;
            y ^= (y & (1 << (5 - j))) ? (1 << (5 - t)) : 0;
        }
        perm1 = y;
    }

    // ---- classical branches: accumulate combined (short+long) linear sums ----
    float acc[SPW][6];
#pragma unroll
    for (int i = 0; i < SPW; i++)
#pragma unroll
        for (int q = 0; q < 6; q++) acc[i][q] = 0.f;

    // short branch: lane = position w in [0,64); 4 channels per float4 read
    {
        float xm1[SPW], xp1[SPW];
#pragma unroll
        for (int i = 0; i < SPW; i++) {
            float lft = __shfl(xsv[i], (lane + 63) & 63, 64);
            float rgt = __shfl(xsv[i], (lane + 1) & 63, 64);
            xm1[i] = (lane == 0)  ? 0.f : lft;
            xp1[i] = (lane == 63) ? 0.f : rgt;
        }
        const float4* lsw_s4 = reinterpret_cast<const float4*>(lsw_s);
#pragma unroll
        for (int c4 = 0; c4 < 4; c4++) {
            float h[4][SPW];
#pragma unroll
            for (int cc = 0; cc < 4; cc++) {
                const int c = c4 * 4 + cc;
                float w0 = csw[c * 3 + 0], w1 = csw[c * 3 + 1], w2 = csw[c * 3 + 2];
                float bb = csb[c];
#pragma unroll
                for (int i = 0; i < SPW; i++)
                    h[cc][i] = fmaxf(0.f,
                        fmaf(w0, xm1[i], fmaf(w1, xsv[i], fmaf(w2, xp1[i], bb))));
            }
#pragma unroll
            for (int q = 0; q < 6; q++) {
                float4 wv = lsw_s4[(q * 4 + c4) * 64 + lane];
#pragma unroll
                for (int i = 0; i < SPW; i++)
                    acc[i][q] = fmaf(h[0][i], wv.x, fmaf(h[1][i], wv.y,
                                fmaf(h[2][i], wv.z, fmaf(h[3][i], wv.w, acc[i][q]))));
            }
        }
    }

    // long branch: lane owns positions lane*4..lane*4+3; 2 channels per float4
    {
        float l2v[SPW], l1v[SPW], r1v[SPW], r2v[SPW];
#pragma unroll
        for (int i = 0; i < SPW; i++) {
            float a = __shfl(xlv[i].z, (lane + 63) & 63, 64);
            float b = __shfl(xlv[i].w, (lane + 63) & 63, 64);
            float c = __shfl(xlv[i].x, (lane + 1) & 63, 64);
            float d = __shfl(xlv[i].y, (lane + 1) & 63, 64);
            l2v[i] = (lane == 0)  ? 0.f : a;
            l1v[i] = (lane == 0)  ? 0.f : b;
            r1v[i] = (lane == 63) ? 0.f : c;
            r2v[i] = (lane == 63) ? 0.f : d;
        }
        const float4* llw_s4 = reinterpret_cast<const float4*>(llw_s);
#pragma unroll
        for (int c2 = 0; c2 < 8; c2++) {
            float p0[2][SPW], p1[2][SPW];
#pragma unroll
            for (int cc = 0; cc < 2; cc++) {
                const int c = c2 * 2 + cc;
                float w0 = clw[c * 5 + 0], w1 = clw[c * 5 + 1], w2 = clw[c * 5 + 2];
                float w3 = clw[c * 5 + 3], w4 = clw[c * 5 + 4];
                float bb = clb[c];
#pragma unroll
                for (int i = 0; i < SPW; i++) {
                    float vx = xlv[i].x, vy = xlv[i].y, vz = xlv[i].z, vw = xlv[i].w;
                    float h0 = fmaf(w0, l2v[i], fmaf(w1, l1v[i], fmaf(w2, vx, fmaf(w3, vy, fmaf(w4, vz, bb)))));
                    float h1 = fmaf(w0, l1v[i], fmaf(w1, vx, fmaf(w2, vy, fmaf(w3, vz, fmaf(w4, vw, bb)))));
                    float h2 = fmaf(w0, vx, fmaf(w1, vy, fmaf(w2, vz, fmaf(w3, vw, fmaf(w4, r1v[i], bb)))));
                    float h3 = fmaf(w0, vy, fmaf(w1, vz, fmaf(w2, vw, fmaf(w3, r1v[i], fmaf(w4, r2v[i], bb)))));
                    // relu(max(a,b)) == max(relu(a),relu(b))  (monotone)
                    p0[cc][i] = fmaxf(fmaxf(h0, h1), 0.f);
                    p1[cc][i] = fmaxf(fmaxf(h2, h3), 0.f);
                }
            }
#pragma unroll
            for (int q = 0; q < 6; q++) {
                float4 wv = llw_s4[(q * 8 + c2) * 64 + lane];
#pragma unroll
                for (int i = 0; i < SPW; i++)
                    acc[i][q] = fmaf(p0[0][i], wv.x, fmaf(p1[0][i], wv.y,
                                fmaf(p0[1][i], wv.z, fmaf(p1[1][i], wv.w, acc[i][q]))));
            }
        }
    }

    // ---- reduce-scatter fold: 12 wave-sums in 17 shuffles ----
    // v[0..5]=sample0 q0..5, v[6..11]=sample1 q0..5, v[12..15]=0.
    // After stages (mask 1,2,4,8) value j's total lives at lanes with low 4
    // bits bitrev4(j); xor-16/32 finish. 12 totals in one reg -> readlane.
    float fv[12];
    {
        float v[16];
#pragma unroll
        for (int q = 0; q < 6; q++) { v[q] = acc[0][q]; v[6 + q] = acc[1][q]; }
        v[12] = 0.f; v[13] = 0.f; v[14] = 0.f; v[15] = 0.f;
        {
            const bool hi = lane & 1;
#pragma unroll
            for (int j = 0; j < 8; j++) {
                float snd = hi ? v[j] : v[j + 8];
                float rcv = __shfl_xor(snd, 1, 64);
                float kept = hi ? v[j + 8] : v[j];
                v[j] = kept + rcv;
            }
        }
        {
            const bool hi = lane & 2;
#pragma unroll
            for (int j = 0; j < 4; j++) {
                float snd = hi ? v[j] : v[j + 4];
                float rcv = __shfl_xor(snd, 2, 64);
                float kept = hi ? v[j + 4] : v[j];
                v[j] = kept + rcv;
            }
        }
        {
            const bool hi = lane & 4;
#pragma unroll
            for (int j = 0; j < 2; j++) {
                float snd = hi ? v[j] : v[j + 2];
                float rcv = __shfl_xor(snd, 4, 64);
                float kept = hi ? v[j + 2] : v[j];
                v[j] = kept + rcv;
            }
        }
        {
            const bool hi = lane & 8;
            float snd = hi ? v[0] : v[1];
            float rcv = __shfl_xor(snd, 8, 64);
            float kept = hi ? v[1] : v[0];
            v[0] = kept + rcv;
        }
        float r = v[0];
        r += __shfl_xor(r, 16, 64);
        r += __shfl_xor(r, 32, 64);
        const int rl[12] = {0, 8, 4, 12, 2, 10, 6, 14, 1, 9, 5, 13};
#pragma unroll
        for (int j = 0; j < 12; j++)
            fv[j] = __int_as_float(
                __builtin_amdgcn_readlane(__float_as_int(r), rl[j]));
    }
    float f[SPW][6];
#pragma unroll
    for (int i = 0; i < SPW; i++)
#pragma unroll
        for (int q = 0; q < 6; q++)
            f[i][q] = 0.5f * (fv[i * 6 + q] + lsb[q] + llb[q]);

    // ---- quantum circuit: 64 amplitudes == 64 lanes (wire j <-> bit 5-j) ----
    float ar[SPW], ai[SPW];
#pragma unroll
    for (int i = 0; i < SPW; i++) { ar[i] = 1.f; ai[i] = 0.f; }
#pragma unroll
    for (int j = 0; j < 6; j++) {
        const int mask = 1 << (5 - j);
#pragma unroll
        for (int i = 0; i < SPW; i++) {
            float th = 1.57079632679489662f * f[i][j];
            float ss = __sinf(th), cc = __cosf(th);
            ar[i] *= (lane & mask) ? ss : cc;
        }
    }

#define APPLY_GATE(L, J) do {                                              \
        const int _mask = 1 << (5 - (J));                                  \
        const int _bit = (lane & _mask) ? 1 : 0;                           \
        float4 g = gme[((L) * 6 + (J)) * 2 + _bit];                        \
        _Pragma("unroll")                                                  \
        for (int i = 0; i < SPW; i++) {                                    \
            float br = __shfl_xor(ar[i], _mask, 64);                       \
            float bi = __shfl_xor(ai[i], _mask, 64);                       \
            float nr = g.x * ar[i] - g.y * ai[i] + g.z * br - g.w * bi;    \
            float ni = g.x * ai[i] + g.y * ar[i] + g.z * bi + g.w * br;    \
            ar[i] = nr; ai[i] = ni;                                        \
        } } while (0)

    APPLY_GATE(0, 0); APPLY_GATE(0, 1); APPLY_GATE(0, 2);
    APPLY_GATE(0, 3); APPLY_GATE(0, 4); APPLY_GATE(0, 5);
#pragma unroll
    for (int i = 0; i < SPW; i++) {
        float pr = __shfl(ar[i], perm0, 64);
        float pi2 = __shfl(ai[i], perm0, 64);
        ar[i] = pr; ai[i] = pi2;
    }
    APPLY_GATE(1, 0); APPLY_GATE(1, 1); APPLY_GATE(1, 2);
    APPLY_GATE(1, 3); APPLY_GATE(1, 4); APPLY_GATE(1, 5);
#pragma unroll
    for (int i = 0; i < SPW; i++) {
        float pr = __shfl(ar[i], perm1, 64);
        float pi2 = __shfl(ai[i], perm1, 64);
        ar[i] = pr; ai[i] = pi2;
    }

    float outv[SPW];
#pragma unroll
    for (int i = 0; i < SPW; i++) {
        // all six <Z_k> via Walsh-Hadamard butterfly; z[k] lands in lane 32>>k
        float v = ar[i] * ar[i] + ai[i] * ai[i];
#pragma unroll
        for (int m = 1; m < 64; m <<= 1) {
            float pp = __shfl_xor(v, m, 64);
            v = (lane & m) ? (pp - v) : (v + pp);
        }
        float z[6];
#pragma unroll
        for (int k = 0; k < 6; k++)
            z[k] = __int_as_float(
                __builtin_amdgcn_readlane(__float_as_int(v), 32 >> k));
        // fc head (uniform, computed redundantly per lane)
        float o = fc2b[0];
#pragma unroll
        for (int m = 0; m < 8; m++) {
            float h = fc1b[m];
#pragma unroll
            for (int k = 0; k < 6; k++) h = fmaf(fc1w[m * 6 + k], z[k], h);
            h = fmaxf(h, 0.f);
            o = fmaf(fc2w[m], h, o);
        }
        outv[i] = o;
    }

    if (lane == 0) {
#pragma unroll
        for (int i = 0; i < SPW; i++)
            if (base + i < B) out[base + i] = outv[i];
    }
}

extern "C" void kernel_launch(void* const* d_in, const int* in_sizes, int n_in,
                              void* d_out, int out_size, void* d_ws, size_t ws_size,
                              hipStream_t stream) {
    const float* xs   = (const float*)d_in[0];
    const float* xl   = (const float*)d_in[1];
    const float* csw  = (const float*)d_in[2];
    const float* csb  = (const float*)d_in[3];
    const float* lsw  = (const float*)d_in[4];
    const float* lsb  = (const float*)d_in[5];
    const float* clw  = (const float*)d_in[6];
    const float* clb  = (const float*)d_in[7];
    const float* llw  = (const float*)d_in[8];
    const float* llb  = (const float*)d_in[9];
    const float* qw   = (const float*)d_in[10];
    const float* fc1w = (const float*)d_in[11];
    const float* fc1b = (const float*)d_in[12];
    const float* fc2w = (const float*)d_in[13];
    const float* fc2b = (const float*)d_in[14];
    float* out = (float*)d_out;

    const int B = in_sizes[0] / 64;
    const int spb = WPB * SPW;                    // samples per block
    const int blocks = (B + spb - 1) / spb;
    hybridqrc_kernel<<<blocks, NTHR, 0, stream>>>(
        xs, xl, csw, csb, lsw, lsb, clw, clb, llw, llb,
        qw, fc1w, fc1b, fc2w, fc2b, out, B);
}

// Round 7
// 117.928 us; speedup vs baseline: 1.0112x; 1.0112x over previous
//
#include <hip/hip_runtime.h>
#include <math.h>

#define SPW 4          // samples per wave
#define WPB 8          // waves per block -> 512 threads
#define NTHR (WPB * 64)

__global__ __launch_bounds__(NTHR, 4) void hybridqrc_kernel(
    const float* __restrict__ xs,  const float* __restrict__ xl,
    const float* __restrict__ csw, const float* __restrict__ csb,
    const float* __restrict__ lsw, const float* __restrict__ lsb,
    const float* __restrict__ clw, const float* __restrict__ clb,
    const float* __restrict__ llw, const float* __restrict__ llb,
    const float* __restrict__ qw,  const float* __restrict__ fc1w,
    const float* __restrict__ fc1b,const float* __restrict__ fc2w,
    const float* __restrict__ fc2b,float* __restrict__ out, int B)
{
    // ---- LDS: both linear-weight matrices, channel-interleaved + 12 gates ----
    // lsw_s: [(q*4+c4)*256 + w*4 + (c&3)]  -> float4 read = channels 4c4..4c4+3
    // llw_s: [(q*8+c2)*256 + (j>>1)*4 + (c&1)*2 + (j&1)]
    //        -> float4 read = {p0w,p1w} for channels 2c2, 2c2+1
    __shared__ float lsw_s[6144];    // 24 KB
    __shared__ float llw_s[12288];   // 48 KB  (72.4 KB total -> 2 blocks/CU)
    __shared__ float4 gme[24];       // [gate*2+bit] = (own_r, own_i, oth_r, oth_i)
    const int tid = threadIdx.x;
    const int lane = tid & 63;
    const int wave = blockIdx.x * WPB + (tid >> 6);
    const int base = wave * SPW;

    // issue per-wave input loads early (independent of LDS staging)
    float xsv[SPW];
    float4 xlv[SPW];
#pragma unroll
    for (int i = 0; i < SPW; i++) {
        xsv[i] = xs[(base + i) * 64 + lane];
        xlv[i] = reinterpret_cast<const float4*>(xl + (size_t)(base + i) * 256)[lane];
    }

#pragma unroll
    for (int it = 0; it < 12; it++) {
        int k = it * NTHR + tid;                 // k = q*1024 + c*64 + w
        int w = k & 63, c = (k >> 6) & 15, q = k >> 10;
        lsw_s[(q * 4 + (c >> 2)) * 256 + w * 4 + (c & 3)] = lsw[k];
    }
#pragma unroll
    for (int it = 0; it < 24; it++) {
        int k = it * NTHR + tid;                 // k = q*2048 + c*128 + j
        int j = k & 127, c = (k >> 7) & 15, q = k >> 11;
        llw_s[(q * 8 + (c >> 1)) * 256 + (j >> 1) * 4 + (c & 1) * 2 + (j & 1)] = llw[k];
    }
    if (tid < 24) {
        int g = tid >> 1, bit = tid & 1;
        float phi = qw[g * 3 + 0], th = qw[g * 3 + 1], om = qw[g * 3 + 2];
        float a = 0.5f * (phi + om), b = 0.5f * (phi - om);
        float ca = cosf(a), sa = sinf(a);
        float cb = cosf(b), sb = sinf(b);
        float ct = cosf(0.5f * th), st = sinf(0.5f * th);
        float4 v;
        if (bit) { v.x = ca * ct; v.y =  sa * ct; v.z =  cb * st; v.w = -sb * st; }
        else     { v.x = ca * ct; v.y = -sa * ct; v.z = -cb * st; v.w = -sb * st; }
        gme[tid] = v;
    }
    __syncthreads();

    if (base >= B) return;

    // ---- fused CNOT-ring permutations (lane-only, sample-independent) ----
    int perm0, perm1;
    {
        int y = lane;
#pragma unroll
        for (int j = 5; j >= 0; j--) {
            const int t = (j + 1) % 6;
            y ^= (y & (1 << (5 - j))) ? (1 << (5 - t)) : 0;
        }
        perm0 = y;
        y = lane;
#pragma unroll
        for (int j = 5; j >= 0; j--) {
            const int t = (j + 2) % 6;
            y ^= (y & (1 << (5 - j))) ? (1 << (5 - t)) : 0;
        }
        perm1 = y;
    }

    // ---- classical branches: accumulate combined (short+long) linear sums ----
    float acc[SPW][6];
#pragma unroll
    for (int i = 0; i < SPW; i++)
#pragma unroll
        for (int q = 0; q < 6; q++) acc[i][q] = 0.f;

    // short branch: lane = position w in [0,64); 4 channels per float4 read
    {
        float xm1[SPW], xp1[SPW];
#pragma unroll
        for (int i = 0; i < SPW; i++) {
            float lft = __shfl(xsv[i], (lane + 63) & 63, 64);
            float rgt = __shfl(xsv[i], (lane + 1) & 63, 64);
            xm1[i] = (lane == 0)  ? 0.f : lft;
            xp1[i] = (lane == 63) ? 0.f : rgt;
        }
        const float4* lsw_s4 = reinterpret_cast<const float4*>(lsw_s);
#pragma unroll
        for (int c4 = 0; c4 < 4; c4++) {
            float h[4][SPW];
#pragma unroll
            for (int cc = 0; cc < 4; cc++) {
                const int c = c4 * 4 + cc;
                float w0 = csw[c * 3 + 0], w1 = csw[c * 3 + 1], w2 = csw[c * 3 + 2];
                float bb = csb[c];
#pragma unroll
                for (int i = 0; i < SPW; i++)
                    h[cc][i] = fmaxf(0.f,
                        fmaf(w0, xm1[i], fmaf(w1, xsv[i], fmaf(w2, xp1[i], bb))));
            }
#pragma unroll
            for (int q = 0; q < 6; q++) {
                float4 wv = lsw_s4[(q * 4 + c4) * 64 + lane];
#pragma unroll
                for (int i = 0; i < SPW; i++)
                    acc[i][q] = fmaf(h[0][i], wv.x, fmaf(h[1][i], wv.y,
                                fmaf(h[2][i], wv.z, fmaf(h[3][i], wv.w, acc[i][q]))));
            }
        }
    }

    // long branch: lane owns positions lane*4..lane*4+3; 2 channels per float4
    {
        float l2v[SPW], l1v[SPW], r1v[SPW], r2v[SPW];
#pragma unroll
        for (int i = 0; i < SPW; i++) {
            float a = __shfl(xlv[i].z, (lane + 63) & 63, 64);
            float b = __shfl(xlv[i].w, (lane + 63) & 63, 64);
            float c = __shfl(xlv[i].x, (lane + 1) & 63, 64);
            float d = __shfl(xlv[i].y, (lane + 1) & 63, 64);
            l2v[i] = (lane == 0)  ? 0.f : a;
            l1v[i] = (lane == 0)  ? 0.f : b;
            r1v[i] = (lane == 63) ? 0.f : c;
            r2v[i] = (lane == 63) ? 0.f : d;
        }
        const float4* llw_s4 = reinterpret_cast<const float4*>(llw_s);
#pragma unroll
        for (int c2 = 0; c2 < 8; c2++) {
            float p0[2][SPW], p1[2][SPW];
#pragma unroll
            for (int cc = 0; cc < 2; cc++) {
                const int c = c2 * 2 + cc;
                float w0 = clw[c * 5 + 0], w1 = clw[c * 5 + 1], w2 = clw[c * 5 + 2];
                float w3 = clw[c * 5 + 3], w4 = clw[c * 5 + 4];
                float bb = clb[c];
#pragma unroll
                for (int i = 0; i < SPW; i++) {
                    float vx = xlv[i].x, vy = xlv[i].y, vz = xlv[i].z, vw = xlv[i].w;
                    float h0 = fmaf(w0, l2v[i], fmaf(w1, l1v[i], fmaf(w2, vx, fmaf(w3, vy, fmaf(w4, vz, bb)))));
                    float h1 = fmaf(w0, l1v[i], fmaf(w1, vx, fmaf(w2, vy, fmaf(w3, vz, fmaf(w4, vw, bb)))));
                    float h2 = fmaf(w0, vx, fmaf(w1, vy, fmaf(w2, vz, fmaf(w3, vw, fmaf(w4, r1v[i], bb)))));
                    float h3 = fmaf(w0, vy, fmaf(w1, vz, fmaf(w2, vw, fmaf(w3, r1v[i], fmaf(w4, r2v[i], bb)))));
                    // relu(max(a,b)) == max(relu(a),relu(b))  (monotone)
                    p0[cc][i] = fmaxf(fmaxf(h0, h1), 0.f);
                    p1[cc][i] = fmaxf(fmaxf(h2, h3), 0.f);
                }
            }
#pragma unroll
            for (int q = 0; q < 6; q++) {
                float4 wv = llw_s4[(q * 8 + c2) * 64 + lane];
#pragma unroll
                for (int i = 0; i < SPW; i++)
                    acc[i][q] = fmaf(p0[0][i], wv.x, fmaf(p1[0][i], wv.y,
                                fmaf(p0[1][i], wv.z, fmaf(p1[1][i], wv.w, acc[i][q]))));
            }
        }
    }

    // ---- reduce-scatter fold: 24 wave-sums in 32 shuffles ----
    // v[0..23] = acc[i][q] (i*6+q), v[24..31]=0. Stages mask 1,2,4,8,16 halve
    // the value set; xor-32 finishes. Value j's total lands in the lanes whose
    // low 5 bits equal bitrev5(j) -> readlane broadcasts (no DS ops).
    float fv[24];
    {
        float v[32];
#pragma unroll
        for (int i = 0; i < SPW; i++)
#pragma unroll
            for (int q = 0; q < 6; q++) v[i * 6 + q] = acc[i][q];
#pragma unroll
        for (int j = 24; j < 32; j++) v[j] = 0.f;
        {
            const bool hi = lane & 1;
#pragma unroll
            for (int j = 0; j < 16; j++) {
                float snd = hi ? v[j] : v[j + 16];
                float rcv = __shfl_xor(snd, 1, 64);
                float kept = hi ? v[j + 16] : v[j];
                v[j] = kept + rcv;
            }
        }
        {
            const bool hi = lane & 2;
#pragma unroll
            for (int j = 0; j < 8; j++) {
                float snd = hi ? v[j] : v[j + 8];
                float rcv = __shfl_xor(snd, 2, 64);
                float kept = hi ? v[j + 8] : v[j];
                v[j] = kept + rcv;
            }
        }
        {
            const bool hi = lane & 4;
#pragma unroll
            for (int j = 0; j < 4; j++) {
                float snd = hi ? v[j] : v[j + 4];
                float rcv = __shfl_xor(snd, 4, 64);
                float kept = hi ? v[j + 4] : v[j];
                v[j] = kept + rcv;
            }
        }
        {
            const bool hi = lane & 8;
#pragma unroll
            for (int j = 0; j < 2; j++) {
                float snd = hi ? v[j] : v[j + 2];
                float rcv = __shfl_xor(snd, 8, 64);
                float kept = hi ? v[j + 2] : v[j];
                v[j] = kept + rcv;
            }
        }
        {
            const bool hi = lane & 16;
            float snd = hi ? v[0] : v[1];
            float rcv = __shfl_xor(snd, 16, 64);
            float kept = hi ? v[1] : v[0];
            v[0] = kept + rcv;
        }
        float r = v[0];
        r += __shfl_xor(r, 32, 64);
        const int rl[24] = {0,16,8,24,4,20,12,28,2,18,10,26,6,22,14,30,
                            1,17,9,25,5,21,13,29};
#pragma unroll
        for (int j = 0; j < 24; j++)
            fv[j] = __int_as_float(
                __builtin_amdgcn_readlane(__float_as_int(r), rl[j]));
    }
    float f[SPW][6];
#pragma unroll
    for (int i = 0; i < SPW; i++)
#pragma unroll
        for (int q = 0; q < 6; q++)
            f[i][q] = 0.5f * (fv[i * 6 + q] + lsb[q] + llb[q]);

    // ---- quantum circuit: 64 amplitudes == 64 lanes (wire j <-> bit 5-j) ----
    float ar[SPW], ai[SPW];
#pragma unroll
    for (int i = 0; i < SPW; i++) { ar[i] = 1.f; ai[i] = 0.f; }
#pragma unroll
    for (int j = 0; j < 6; j++) {
        const int mask = 1 << (5 - j);
#pragma unroll
        for (int i = 0; i < SPW; i++) {
            float th = 1.57079632679489662f * f[i][j];
            float ss = __sinf(th), cc = __cosf(th);
            ar[i] *= (lane & mask) ? ss : cc;
        }
    }

#define APPLY_GATE(L, J) do {                                              \
        const int _mask = 1 << (5 - (J));                                  \
        const int _bit = (lane & _mask) ? 1 : 0;                           \
        float4 g = gme[((L) * 6 + (J)) * 2 + _bit];                        \
        _Pragma("unroll")                                                  \
        for (int i = 0; i < SPW; i++) {                                    \
            float br = __shfl_xor(ar[i], _mask, 64);                       \
            float bi = __shfl_xor(ai[i], _mask, 64);                       \
            float nr = g.x * ar[i] - g.y * ai[i] + g.z * br - g.w * bi;    \
            float ni = g.x * ai[i] + g.y * ar[i] + g.z * bi + g.w * br;    \
            ar[i] = nr; ai[i] = ni;                                        \
        } } while (0)

    APPLY_GATE(0, 0); APPLY_GATE(0, 1); APPLY_GATE(0, 2);
    APPLY_GATE(0, 3); APPLY_GATE(0, 4); APPLY_GATE(0, 5);
#pragma unroll
    for (int i = 0; i < SPW; i++) {
        float pr = __shfl(ar[i], perm0, 64);
        float pi2 = __shfl(ai[i], perm0, 64);
        ar[i] = pr; ai[i] = pi2;
    }
    APPLY_GATE(1, 0); APPLY_GATE(1, 1); APPLY_GATE(1, 2);
    APPLY_GATE(1, 3); APPLY_GATE(1, 4); APPLY_GATE(1, 5);
#pragma unroll
    for (int i = 0; i < SPW; i++) {
        float pr = __shfl(ar[i], perm1, 64);
        float pi2 = __shfl(ai[i], perm1, 64);
        ar[i] = pr; ai[i] = pi2;
    }

    float outv[SPW];
#pragma unroll
    for (int i = 0; i < SPW; i++) {
        // all six <Z_k> via Walsh-Hadamard butterfly; z[k] lands in lane 32>>k
        float v = ar[i] * ar[i] + ai[i] * ai[i];
#pragma unroll
        for (int m = 1; m < 64; m <<= 1) {
            float pp = __shfl_xor(v, m, 64);
            v = (lane & m) ? (pp - v) : (v + pp);
        }
        float z[6];
#pragma unroll
        for (int k = 0; k < 6; k++)
            z[k] = __int_as_float(
                __builtin_amdgcn_readlane(__float_as_int(v), 32 >> k));
        // fc head (uniform, computed redundantly per lane)
        float o = fc2b[0];
#pragma unroll
        for (int m = 0; m < 8; m++) {
            float h = fc1b[m];
#pragma unroll
            for (int k = 0; k < 6; k++) h = fmaf(fc1w[m * 6 + k], z[k], h);
            h = fmaxf(h, 0.f);
            o = fmaf(fc2w[m], h, o);
        }
        outv[i] = o;
    }

    if (lane == 0) {
#pragma unroll
        for (int i = 0; i < SPW; i++)
            if (base + i < B) out[base + i] = outv[i];
    }
}

extern "C" void kernel_launch(void* const* d_in, const int* in_sizes, int n_in,
                              void* d_out, int out_size, void* d_ws, size_t ws_size,
                              hipStream_t stream) {
    const float* xs   = (const float*)d_in[0];
    const float* xl   = (const float*)d_in[1];
    const float* csw  = (const float*)d_in[2];
    const float* csb  = (const float*)d_in[3];
    const float* lsw  = (const float*)d_in[4];
    const float* lsb  = (const float*)d_in[5];
    const float* clw  = (const float*)d_in[6];
    const float* clb  = (const float*)d_in[7];
    const float* llw  = (const float*)d_in[8];
    const float* llb  = (const float*)d_in[9];
    const float* qw   = (const float*)d_in[10];
    const float* fc1w = (const float*)d_in[11];
    const float* fc1b = (const float*)d_in[12];
    const float* fc2w = (const float*)d_in[13];
    const float* fc2b = (const float*)d_in[14];
    float* out = (float*)d_out;

    const int B = in_sizes[0] / 64;
    const int spb = WPB * SPW;                    // samples per block
    const int blocks = (B + spb - 1) / spb;
    hybridqrc_kernel<<<blocks, NTHR, 0, stream>>>(
        xs, xl, csw, csb, lsw, lsb, clw, clb, llw, llb,
        qw, fc1w, fc1b, fc2w, fc2b, out, B);
}